// Round 2
// baseline (105.813 us; speedup 1.0000x reference)
//
#include <hip/hip_runtime.h>
#include <math.h>

#define BB 8
#define HH 256
#define KK 256
#define EE 128

// DPP-based add: x + dpp_mov(x). Template args keep ctrl a compile-time const.
template <int CTRL, int RM>
__device__ __forceinline__ float dpp_add(float x) {
    int d = __builtin_amdgcn_update_dpp(0, __float_as_int(x), CTRL, RM, 0xf, true);
    return x + __int_as_float(d);
}
// Sum over each 32-lane half; valid in lanes 31 and 63.
__device__ __forceinline__ float dpp_reduce_half(float x) {
    x = dpp_add<0x111, 0xf>(x);  // row_shr:1
    x = dpp_add<0x112, 0xf>(x);  // row_shr:2
    x = dpp_add<0x114, 0xf>(x);  // row_shr:4
    x = dpp_add<0x118, 0xf>(x);  // row_shr:8
    x = dpp_add<0x142, 0xa>(x);  // row_bcast:15 -> lanes 31,63 hold 32-lane sums
    return x;
}
// Sum over all 64 lanes; valid in lane 63.
__device__ __forceinline__ float dpp_reduce_wave(float x) {
    x = dpp_reduce_half(x);
    x = dpp_add<0x143, 0xc>(x);  // row_bcast:31 -> lane 63 holds 64-lane sum
    return x;
}

// ---------------- Kernel U: u[b,h,k] for a 4-h group per block. ----------------
// Key insight: all 256 h-blocks of a given b previously re-gathered the SAME
// 256 key rows (268 MB of L2 traffic total). Here each block computes u for
// 4 h's sharing one pass over the key rows: 512 blocks x 128 KB = 64 MB.
__global__ __launch_bounds__(256) void kvmn_u(
    const float* __restrict__ hidden,     // [B,H,E]
    const float* __restrict__ key_emb,    // [VOCAB,E]
    const int*   __restrict__ key_seq,    // [B,K]
    float* __restrict__ u_ws)             // [B,H,K] (pre-scaled by 1/sqrt(E))
{
    const int bid  = blockIdx.x;          // 0..511
    const int b    = bid >> 6;            // / 64
    const int h0   = (bid & 63) << 2;     // * 4
    const int tid  = threadIdx.x;
    const int w    = tid >> 6;
    const int lane = tid & 63;
    const int half = lane >> 5;
    const int sub  = lane & 31;

    const int ksreg = key_seq[b * KK + tid];   // coalesced; k == tid

    // hidden fragments for the 4 h's (e = sub*4 .. sub*4+3)
    const float4 hq0 = *(const float4*)&hidden[(size_t)(b * HH + h0 + 0) * EE + sub * 4];
    const float4 hq1 = *(const float4*)&hidden[(size_t)(b * HH + h0 + 1) * EE + sub * 4];
    const float4 hq2 = *(const float4*)&hidden[(size_t)(b * HH + h0 + 2) * EE + sub * 4];
    const float4 hq3 = *(const float4*)&hidden[(size_t)(b * HH + h0 + 3) * EE + sub * 4];

    const float inv_scale = 0.08838834764831845f; // 1/sqrt(128)
    float* ub = u_ws + (size_t)(b * HH + h0) * KK;

    #pragma unroll 8
    for (int i = 0; i < 32; ++i) {
        const int    k   = w * 64 + half * 32 + i;
        const int    row = __shfl(ksreg, half * 32 + i, 64);
        const float4 kv  = *(const float4*)&key_emb[(size_t)row * EE + sub * 4];
        float p0 = kv.x * hq0.x + kv.y * hq0.y + kv.z * hq0.z + kv.w * hq0.w;
        float p1 = kv.x * hq1.x + kv.y * hq1.y + kv.z * hq1.z + kv.w * hq1.w;
        float p2 = kv.x * hq2.x + kv.y * hq2.y + kv.z * hq2.z + kv.w * hq2.w;
        float p3 = kv.x * hq3.x + kv.y * hq3.y + kv.z * hq3.z + kv.w * hq3.w;
        // same reduce order + post-reduce scale as before -> identical numerics
        p0 = dpp_reduce_half(p0) * inv_scale;
        p1 = dpp_reduce_half(p1) * inv_scale;
        p2 = dpp_reduce_half(p2) * inv_scale;
        p3 = dpp_reduce_half(p3) * inv_scale;
        if (sub == 31) {                  // lanes 31 and 63 hold the two k-sums
            ub[0 * KK + k] = p0;
            ub[1 * KK + k] = p1;
            ub[2 * KK + k] = p2;
            ub[3 * KK + k] = p3;
        }
    }
}

// ---------------- Kernel A': exp-normalize + value gather; one block per (b,h). ----------------
// Phase 1 removed: u comes from u_ws (coalesced 4B/thread). This kernel is now
// bounded by the irreducible phase-3 value gather (268 MB of L2 reads).
__global__ __launch_bounds__(256) void kvmn_attn(
    const float* __restrict__ value_emb,  // [FVOCAB,E]
    const int*   __restrict__ value_seq,  // [B,H,K]
    const int*   __restrict__ mask,       // [B,H,K]
    const float* __restrict__ u_ws,       // [B,H,K]
    float* __restrict__ o_ws)             // [B,H,E]
{
    __shared__ float  sh_part[4];
    __shared__ float4 sh_o4[8][32];

    const int bid  = blockIdx.x;
    const int b    = bid >> 8;            // / HH
    const int h    = bid & 255;           // % HH
    const int tid  = threadIdx.x;
    const int w    = tid >> 6;
    const int lane = tid & 63;
    const int half = lane >> 5;
    const int sub  = lane & 31;

    const size_t bh = (size_t)(b * HH + h);
    const int   vsreg   = value_seq[bh * KK + tid];
    const int   voff    = vsreg << 7;     // row offset in floats (*EE)
    const int   my_mask = mask[bh * KK + tid];
    const float u       = u_ws[bh * KK + tid];

    // d = exp(u)*mask; denom; p stays in register pk (lane k == tid)
    const float d = expf(u) * (float)my_mask;
    float s = dpp_reduce_wave(d);
    if (lane == 63) sh_part[w] = s;
    __syncthreads();
    const float denom = sh_part[0] + sh_part[1] + sh_part[2] + sh_part[3];
    const float pk = d * (1.0f / (denom + 1e-10f));

    // o[e] = sum_k p[k]*value_emb[vs[k]][e]; idx+p broadcast via __shfl
    float4 acc = make_float4(0.f, 0.f, 0.f, 0.f);
    #pragma unroll 16
    for (int i = 0; i < 32; ++i) {
        const int    src = half * 32 + i;
        const float  p   = __shfl(pk, src, 64);
        const int    ro  = __shfl(voff, src, 64);
        const float4 v   = *(const float4*)&value_emb[(size_t)ro + sub * 4];
        acc.x += p * v.x;
        acc.y += p * v.y;
        acc.z += p * v.z;
        acc.w += p * v.w;
    }
    sh_o4[w * 2 + half][sub] = acc;
    __syncthreads();

    // combine 8 partials, plain coalesced store
    if (tid < 32) {
        float4 t = sh_o4[0][tid];
        #pragma unroll
        for (int r = 1; r < 8; ++r) {
            const float4 q = sh_o4[r][tid];
            t.x += q.x; t.y += q.y; t.z += q.z; t.w += q.w;
        }
        *(float4*)&o_ws[bh * EE + tid * 4] = t;
    }
}

// ---------------- Kernel B: reduce over H + nonzero-count average. ----------------
__global__ __launch_bounds__(256) void kvmn_reduce(
    const float* __restrict__ o_ws,      // [B,H,E]
    float* __restrict__ out)             // [B,E]
{
    __shared__ float sh_sum[256];
    __shared__ int   sh_cnt[256];

    const int b  = blockIdx.x;
    const int t  = threadIdx.x;
    const int e  = t & 127;
    const int hh = t >> 7;

    float sum = 0.0f;
    int   cnt = 0;
    const float* base = o_ws + (size_t)(b * HH + hh * 128) * EE + e;
    #pragma unroll 8
    for (int h = 0; h < 128; ++h) {
        const float v = base[(size_t)h * EE];
        sum += v;
        cnt += (v != 0.0f) ? 1 : 0;
    }
    sh_sum[t] = sum;
    sh_cnt[t] = cnt;
    __syncthreads();
    if (t < 128) {
        const float s = sh_sum[t] + sh_sum[t + 128];
        const int   c = sh_cnt[t] + sh_cnt[t + 128];
        out[b * EE + t] = s / (float)c;
    }
}

extern "C" void kernel_launch(void* const* d_in, const int* in_sizes, int n_in,
                              void* d_out, int out_size, void* d_ws, size_t ws_size,
                              hipStream_t stream) {
    const float* hidden    = (const float*)d_in[0];
    const float* key_emb   = (const float*)d_in[1];
    const float* value_emb = (const float*)d_in[2];
    const int*   key_seq   = (const int*)d_in[3];
    const int*   value_seq = (const int*)d_in[4];
    const int*   mask      = (const int*)d_in[5];

    float* o_ws = (float*)d_ws;                        // [B,H,E]  = 1 MB
    float* u_ws = (float*)d_ws + (size_t)BB * HH * EE; // [B,H,K]  = 2 MB

    kvmn_u<<<BB * 64, 256, 0, stream>>>(hidden, key_emb, key_seq, u_ws);
    kvmn_attn<<<BB * HH, 256, 0, stream>>>(value_emb, value_seq, mask, u_ws, o_ws);
    kvmn_reduce<<<BB, 256, 0, stream>>>(o_ws, (float*)d_out);
    (void)in_sizes; (void)n_in; (void)out_size; (void)ws_size;
}